// Round 1
// baseline (136.474 us; speedup 1.0000x reference)
//
#include <hip/hip_runtime.h>
#include <math.h>

// Problem: out[b,i,p] = sqrt(yr^2 + yi^2),
//   yr = (Hr[b] @ x[b]) * scale + nr*0.01, yi = (Hi[b] @ x[b]) * scale + ni*0.01
// B=32, C=256, HW=3136 (56x56). scale = 1/sqrt(2C) = 1/sqrt(512).
// Memory-bound (~530 MB total vs ~26 GFLOP): fully fused single kernel.

#define NB 32
#define NC 256
#define NP 3136        // 56*56
#define BM 128
#define BN 64
#define BK 32
#define LDH 40         // padded LDS stride (bf16 elems) for H tiles
#define LDX 40         // padded LDS stride for transposed x tile
#define NBN (NP / BN)  // 49

typedef __attribute__((ext_vector_type(8))) short short8;
typedef __attribute__((ext_vector_type(4))) float f32x4;

// fp32 -> bf16 round-to-nearest-even, bit-exact, no type-support risk
static __device__ __forceinline__ unsigned short f2bf(float f) {
  unsigned int u = __float_as_uint(f);
  u += 0x7fffu + ((u >> 16) & 1u);
  return (unsigned short)(u >> 16);
}

__global__ __launch_bounds__(256)
void rayleigh_gemm_kernel(const float* __restrict__ xg,
                          const float* __restrict__ Hrg,
                          const float* __restrict__ Hig,
                          const float* __restrict__ nrg,
                          const float* __restrict__ nig,
                          float* __restrict__ outg)
{
  __shared__ unsigned short hr_lds[BM * LDH];
  __shared__ unsigned short hi_lds[BM * LDH];
  __shared__ unsigned short x_lds[BN * LDX];

  const int bid = blockIdx.x;
  const int bn  = bid % NBN;       // N tile (fastest -> H tile reused in L2)
  const int t2  = bid / NBN;
  const int bm  = t2 & 1;          // M tile (0..1)
  const int b   = t2 >> 1;         // batch

  const int tid  = threadIdx.x;
  const int lane = tid & 63;
  const int wave = tid >> 6;       // 4 waves: 2 (M) x 2 (N)
  const int wm   = wave >> 1;
  const int wn   = wave & 1;
  const int fr   = lane & 15;      // A-row / B-col / D-col within 16
  const int fq   = lane >> 4;      // k-chunk (A/B), row-quad (D)

  f32x4 accR[4][2], accI[4][2];
  #pragma unroll
  for (int m = 0; m < 4; ++m)
    #pragma unroll
    for (int n = 0; n < 2; ++n) {
      accR[m][n] = (f32x4){0.f, 0.f, 0.f, 0.f};
      accI[m][n] = (f32x4){0.f, 0.f, 0.f, 0.f};
    }

  const float* hr_base = Hrg + ((size_t)b * NC + (size_t)bm * BM) * NC;
  const float* hi_base = Hig + ((size_t)b * NC + (size_t)bm * BM) * NC;
  const float* x_base  = xg  + (size_t)b * NC * NP + (size_t)bn * BN;

  const int h_c = (tid & 7) * 4;   // k offset within H tile (8 lanes x float4 = 32)
  const int h_r = tid >> 3;        // 0..31, 4 passes -> 128 rows
  const int x_c = (tid & 15) * 4;  // p offset within x tile (16 lanes x float4 = 64)
  const int x_r = tid >> 4;        // 0..15 (k), 2 passes -> 32 k

  for (int k0 = 0; k0 < NC; k0 += BK) {
    __syncthreads();  // protect LDS against previous iteration's readers

    // ---- stage Hr, Hi tiles: 128 rows x 32 k, fp32 -> bf16 ----
    #pragma unroll
    for (int pass = 0; pass < 4; ++pass) {
      const int row = h_r + pass * 32;
      const float4 vr = *reinterpret_cast<const float4*>(hr_base + (size_t)row * NC + k0 + h_c);
      const float4 vi = *reinterpret_cast<const float4*>(hi_base + (size_t)row * NC + k0 + h_c);
      const unsigned int r01 = (unsigned int)f2bf(vr.x) | ((unsigned int)f2bf(vr.y) << 16);
      const unsigned int r23 = (unsigned int)f2bf(vr.z) | ((unsigned int)f2bf(vr.w) << 16);
      const unsigned int i01 = (unsigned int)f2bf(vi.x) | ((unsigned int)f2bf(vi.y) << 16);
      const unsigned int i23 = (unsigned int)f2bf(vi.z) | ((unsigned int)f2bf(vi.w) << 16);
      *reinterpret_cast<uint2*>(&hr_lds[row * LDH + h_c]) = make_uint2(r01, r23);
      *reinterpret_cast<uint2*>(&hi_lds[row * LDH + h_c]) = make_uint2(i01, i23);
    }

    // ---- stage x tile TRANSPOSED: x_lds[p][k], 64 x 32, k-chunk XOR swizzle ----
    #pragma unroll
    for (int pass = 0; pass < 2; ++pass) {
      const int k = x_r + pass * 16;
      const float4 v = *reinterpret_cast<const float4*>(x_base + (size_t)(k0 + k) * NP + x_c);
      const float vv[4] = {v.x, v.y, v.z, v.w};
      #pragma unroll
      for (int j = 0; j < 4; ++j) {
        const int p  = x_c + j;
        const int ks = k ^ (((p >> 2) & 3) << 3);  // swizzle k's chunk by p-bits
        x_lds[p * LDX + ks] = f2bf(vv[j]);
      }
    }
    __syncthreads();

    // ---- fragments: contiguous 8 bf16 along k per lane (ds_read_b128) ----
    short8 ar[4], ai[4], xb[2];
    #pragma unroll
    for (int m = 0; m < 4; ++m) {
      const int row = wm * 64 + m * 16 + fr;
      ar[m] = *reinterpret_cast<const short8*>(&hr_lds[row * LDH + fq * 8]);
      ai[m] = *reinterpret_cast<const short8*>(&hi_lds[row * LDH + fq * 8]);
    }
    #pragma unroll
    for (int n = 0; n < 2; ++n) {
      const int p = wn * 32 + n * 16 + fr;
      const int q = fq ^ ((p >> 2) & 3);  // undo the k-chunk swizzle
      xb[n] = *reinterpret_cast<const short8*>(&x_lds[p * LDX + q * 8]);
    }

    #pragma unroll
    for (int m = 0; m < 4; ++m)
      #pragma unroll
      for (int n = 0; n < 2; ++n) {
        accR[m][n] = __builtin_amdgcn_mfma_f32_16x16x32_bf16(ar[m], xb[n], accR[m][n], 0, 0, 0);
        accI[m][n] = __builtin_amdgcn_mfma_f32_16x16x32_bf16(ai[m], xb[n], accI[m][n], 0, 0, 0);
      }
  }

  // ---- fused epilogue: scale, add noise, magnitude ----
  const float scale = 0.04419417382415922f;  // 1/sqrt(512)
  const float nstd  = 0.01f;
  #pragma unroll
  for (int m = 0; m < 4; ++m) {
    const int row0 = bm * BM + wm * 64 + m * 16 + fq * 4;
    #pragma unroll
    for (int n = 0; n < 2; ++n) {
      const int col = bn * BN + wn * 32 + n * 16 + fr;
      const size_t base = ((size_t)b * NC + row0) * NP + col;
      #pragma unroll
      for (int r = 0; r < 4; ++r) {
        const size_t idx = base + (size_t)r * NP;
        const float yr = accR[m][n][r] * scale + nrg[idx] * nstd;
        const float yi = accI[m][n][r] * scale + nig[idx] * nstd;
        outg[idx] = sqrtf(yr * yr + yi * yi);
      }
    }
  }
}

extern "C" void kernel_launch(void* const* d_in, const int* in_sizes, int n_in,
                              void* d_out, int out_size, void* d_ws, size_t ws_size,
                              hipStream_t stream) {
  const float* x  = (const float*)d_in[0];
  const float* Hr = (const float*)d_in[1];
  const float* Hi = (const float*)d_in[2];
  const float* nr = (const float*)d_in[3];
  const float* ni = (const float*)d_in[4];
  float* out = (float*)d_out;

  dim3 grid(NB * 2 * NBN);  // 32 batches x 2 M-tiles x 49 N-tiles = 3136 blocks
  dim3 block(256);
  hipLaunchKernelGGL(rayleigh_gemm_kernel, grid, block, 0, stream,
                     x, Hr, Hi, nr, ni, out);
}